// Round 4
// baseline (198.402 us; speedup 1.0000x reference)
//
#include <hip/hip_runtime.h>
#include <hip/hip_bf16.h>

typedef __attribute__((ext_vector_type(8))) short s8v;   // 8 x bf16 = 4 VGPR
typedef __attribute__((ext_vector_type(4))) short s4v;   // 4 x bf16 = 2 VGPR
typedef __attribute__((ext_vector_type(4))) float f4v;   // 4 x f32

static __device__ __forceinline__ short f2bf(float f){
  unsigned int u = __float_as_uint(f);
  u = (u + 0x7FFFu + ((u >> 16) & 1u)) >> 16;   // RNE f32 -> bf16
  return (short)u;
}

static __device__ __forceinline__ s4v pack4(float a, float b, float c, float d){
  union { s4v v; __hip_bfloat162 h[2]; } u;
  u.h[0] = __float22bfloat162_rn(make_float2(a, b));
  u.h[1] = __float22bfloat162_rn(make_float2(c, d));
  return u.v;
}

static __device__ __forceinline__ f4v mfma16(s4v a, s4v b, f4v c){
  return __builtin_amdgcn_mfma_f32_16x16x16bf16_1k(a, b, c, 0, 0, 0);
}

// ---------- K1: h = x @ W (8 rows per wave) ----------
__global__ __launch_bounds__(256) void k_h(const float* __restrict__ x,
                                           const float* __restrict__ W,
                                           float* __restrict__ h){
  int wid = threadIdx.x >> 6, lane = threadIdx.x & 63;
  int r0 = (blockIdx.x * 4 + wid) * 8;
  const float* xr = x + (size_t)r0 * 512;
  float acc[8] = {0.f,0.f,0.f,0.f,0.f,0.f,0.f,0.f};
  #pragma unroll 4
  for (int k = 0; k < 512; ++k){
    float wv = W[k*64 + lane];
    #pragma unroll
    for (int r = 0; r < 8; ++r)
      acc[r] = fmaf(xr[(size_t)r*512 + k], wv, acc[r]);
  }
  #pragma unroll
  for (int r = 0; r < 8; ++r)
    h[(size_t)(r0 + r)*64 + lane] = acc[r];
}

// ---------- K2: per-64-row tile: swizzled V frags, per-row F/EG/V2, block partials ----------
__global__ __launch_bounds__(256) void k_prep(const float* __restrict__ h,
                                              const float* __restrict__ a,
                                              short* __restrict__ VbfSw,
                                              short* __restrict__ VTsw,
                                              float* __restrict__ F,
                                              float2* __restrict__ EG,
                                              float* __restrict__ V2arr,
                                              float* __restrict__ Pv2,
                                              float* __restrict__ Pg,
                                              float* __restrict__ Vpart){
  __shared__ float t[64][65];
  const int tid = threadIdx.x;
  const int lane = tid & 63, w = tid >> 6;
  const int lo = lane & 15, hi = lane >> 4;
  const int i0 = blockIdx.x * 64;
  #pragma unroll
  for (int it = 0; it < 16; ++it){
    int r = w * 16 + it;
    t[r][lane] = h[(size_t)(i0 + r) * 64 + lane];
  }
  __syncthreads();
  // VbfSw: dot A-frag layout
  #pragma unroll
  for (int ks = 0; ks < 2; ++ks){
    s8v o;
    #pragma unroll
    for (int e = 0; e < 8; ++e)
      o[e] = f2bf(t[w*16 + lo][ks*32 + hi*8 + e]);
    *(s8v*)(VbfSw + ((size_t)(i0/16 + w)*2 + ks)*512 + lane*8) = o;
  }
  // VTsw: PV A-frag layout
  const int p = w >> 1;
  #pragma unroll
  for (int oo = 0; oo < 2; ++oo){
    const int ot = (w & 1) * 2 + oo;
    s8v o;
    #pragma unroll
    for (int e = 0; e < 8; ++e){
      int parity = e >> 2, q = e & 3;
      o[e] = f2bf(t[(p*2 + parity)*16 + hi*4 + q][ot*16 + lo]);
    }
    *(s8v*)(VTsw + ((size_t)(i0/32 + p)*4 + ot)*512 + lane*8) = o;
  }
  // per-row stats + block partials + colsum (wave 0)
  if (tid < 64){
    const int r = tid;
    float f = 0.f, g = 0.f, v2 = 0.f;
    #pragma unroll 8
    for (int o = 0; o < 64; ++o){
      float hv = t[r][o];
      f  = fmaf(hv, a[o],      f);
      g  = fmaf(hv, a[64 + o], g);
      v2 = fmaf(hv, hv,        v2);
    }
    const int row = i0 + r;
    F[row] = f;
    V2arr[row] = v2;
    EG[row] = make_float2(__expf(g), __expf(0.2f * g));
    float vmin = v2, gmx = g;
    #pragma unroll
    for (int off = 32; off; off >>= 1){
      vmin = fminf(vmin, __shfl_xor(vmin, off));
      gmx  = fmaxf(gmx,  __shfl_xor(gmx,  off));
    }
    if (r == 0){ Pv2[blockIdx.x] = vmin; Pg[blockIdx.x] = gmx; }
    float cs = 0.f;
    #pragma unroll 8
    for (int rr = 0; rr < 64; ++rr) cs += t[rr][tid];
    Vpart[(size_t)blockIdx.x * 64 + tid] = cs;
  }
}

// ---------- K3: QBLK=32 fused kernel. 256 blocks x 1024 threads (16 waves, 1 block/CU).
// Each V-tile read (VTsw/VbfSw 8KB) feeds TWO 16-row groups -> all L2 streams halved,
// 2x adj bytes in flight for the HBM-latency-bound phase AB. Cross-wave reduction via
// LDS f32 atomics into padded Macc (bank-spread), replacing the 32KB numT round-trip.
__global__ __launch_bounds__(1024, 4) void k_fused(
    const int* __restrict__ adj,
    const float2* __restrict__ EG, const float* __restrict__ V2arr,
    const float* __restrict__ F,
    const float* __restrict__ Pv2, const float* __restrict__ Pg,
    const float* __restrict__ Vpart,
    const short* __restrict__ VbfSw, const short* __restrict__ VTsw,
    unsigned long long* __restrict__ adjbits,
    float* __restrict__ out)
{
  __shared__ float Macc[32][65];          // padded: bank = (65*r + c) % 32 spreads rows
  __shared__ float denA[32];
  __shared__ float Mlds[32][68];
  __shared__ float M1L[32][68];
  __shared__ __align__(16) short Mb16[32][64];
  __shared__ float CiL[32], rm2L[32], uaiL[32];
  __shared__ float VmeanL[64];
  __shared__ float gmaxS, v2minS;
  __shared__ int actL, chgL, emptyL;

  const int tid  = threadIdx.x;
  const int w    = tid >> 6;              // 0..15
  const int lane = tid & 63;
  const int lo = lane & 15, hi = lane >> 4;
  const int r0 = blockIdx.x << 5;         // 32 rows per block
  const int i0 = r0 + lo;
  const int i1 = r0 + 16 + lo;

  // zero accumulators + global min/max from per-block partials
  {
    float* mz = &Macc[0][0];
    for (int k2 = tid; k2 < 32*65; k2 += 1024) mz[k2] = 0.f;
    if (tid < 32) denA[tid] = 0.f;
  }
  if (tid < 64){
    float v = fminf(Pv2[tid], Pv2[tid + 64]);
    float g = fmaxf(Pg[tid],  Pg[tid + 64]);
    #pragma unroll
    for (int off = 32; off; off >>= 1){
      v = fminf(v, __shfl_xor(v, off));
      g = fmaxf(g, __shfl_xor(g, off));
    }
    if (tid == 0){ v2minS = v; gmaxS = g; actL = 0; emptyL = 0; }
  }
  __syncthreads();

  const float fi0 = F[i0], fi1 = F[i1];
  const float gmax = gmaxS;
  const float z0 = fi0 + gmax, z1 = fi1 + gmax;
  const float B0 = fmaxf(z0, 0.2f * z0);
  const float B1 = fmaxf(z1, 0.2f * z1);
  const float e1s0 = __expf(fi0 - B0), e2s0 = __expf(0.2f * fi0 - B0);
  const float e1s1 = __expf(fi1 - B1), e2s1 = __expf(0.2f * fi1 - B1);

  const int* arow0 = adj + (size_t)i0 * 8192 + hi*4;
  const int* arow1 = adj + (size_t)i1 * 8192 + hi*4;

  const f4v zero4 = {0.f,0.f,0.f,0.f};
  f4v pacc0[4] = {zero4, zero4, zero4, zero4};
  f4v pacc1[4] = {zero4, zero4, zero4, zero4};
  float pden0 = 0.f, pden1 = 0.f;

  // ---- Phase AB: softmax denom + A@V for both rowgroups; V-tile read shared ----
  for (int c = w; c < 128; c += 16){
    const int* ap0 = arow0 + (c << 6);
    const int* ap1 = arow1 + (c << 6);
    s4v wp0[4], wp1[4];
    unsigned long long mrow0 = 0ull, mrow1 = 0ull;
    #pragma unroll
    for (int nt = 0; nt < 4; ++nt){
      const int jb = (c << 6) + nt*16 + hi*4;
      const int4 a0 = *(const int4*)(ap0 + nt*16);
      const int4 a1 = *(const int4*)(ap1 + nt*16);
      const f4v u0 = *(const f4v*)(EG + jb);       // eg1_0,eg2_0,eg1_1,eg2_1
      const f4v u1 = *(const f4v*)(EG + jb + 2);
      const float ega[4] = {u0[0], u0[2], u1[0], u1[2]};
      const float egb[4] = {u0[1], u0[3], u1[1], u1[3]};
      const int ab0[4] = {a0.x, a0.y, a0.z, a0.w};
      const int ab1[4] = {a1.x, a1.y, a1.z, a1.w};
      float w0v[4], w1v[4];
      #pragma unroll
      for (int q = 0; q < 4; ++q){
        float u = fmaxf(e1s0 * ega[q], e2s0 * egb[q]);
        u = ab0[q] ? u : 0.f;
        pden0 += u; w0v[q] = u;
        float v = fmaxf(e1s1 * ega[q], e2s1 * egb[q]);
        v = ab1[q] ? v : 0.f;
        pden1 += v; w1v[q] = v;
      }
      const unsigned nib0 = (unsigned)ab0[0] | ((unsigned)ab0[1] << 1)
                          | ((unsigned)ab0[2] << 2) | ((unsigned)ab0[3] << 3);
      const unsigned nib1 = (unsigned)ab1[0] | ((unsigned)ab1[1] << 1)
                          | ((unsigned)ab1[2] << 2) | ((unsigned)ab1[3] << 3);
      mrow0 |= (unsigned long long)nib0 << (nt*16 + hi*4);
      mrow1 |= (unsigned long long)nib1 << (nt*16 + hi*4);
      wp0[nt] = pack4(w0v[0], w0v[1], w0v[2], w0v[3]);
      wp1[nt] = pack4(w1v[0], w1v[1], w1v[2], w1v[3]);
    }
    mrow0 |= __shfl_xor(mrow0, 16); mrow0 |= __shfl_xor(mrow0, 32);
    mrow1 |= __shfl_xor(mrow1, 16); mrow1 |= __shfl_xor(mrow1, 32);
    if (hi == 0) adjbits[(size_t)c * 8192 + i0] = mrow0;
    if (hi == 1) adjbits[(size_t)c * 8192 + i1] = mrow1;

    const short* vt = VTsw + (size_t)c*4096 + lane*8;
    #pragma unroll
    for (int p = 0; p < 2; ++p){
      #pragma unroll
      for (int ot = 0; ot < 4; ++ot){
        s8v v8 = *(const s8v*)(vt + (p*4 + ot)*512);
        s4v aLo = {v8[0], v8[1], v8[2], v8[3]};
        s4v aHi = {v8[4], v8[5], v8[6], v8[7]};
        pacc0[ot] = mfma16(aLo, wp0[2*p],   pacc0[ot]);
        pacc0[ot] = mfma16(aHi, wp0[2*p+1], pacc0[ot]);
        pacc1[ot] = mfma16(aLo, wp1[2*p],   pacc1[ot]);
        pacc1[ot] = mfma16(aHi, wp1[2*p+1], pacc1[ot]);
      }
    }
  }

  // cross-wave reduction via LDS atomics
  pden0 += __shfl_xor(pden0, 16); pden0 += __shfl_xor(pden0, 32);
  pden1 += __shfl_xor(pden1, 16); pden1 += __shfl_xor(pden1, 32);
  if (hi == 0) atomicAdd(&denA[lo],      pden0);
  if (hi == 1) atomicAdd(&denA[16 + lo], pden1);
  #pragma unroll
  for (int ot = 0; ot < 4; ++ot)
    #pragma unroll
    for (int q = 0; q < 4; ++q){
      atomicAdd(&Macc[lo]     [ot*16 + hi*4 + q], pacc0[ot][q]);
      atomicAdd(&Macc[16 + lo][ot*16 + hi*4 + q], pacc1[ot][q]);
    }
  __syncthreads();

  // ---- M1, Ci, empty detection ----
  {
    const int r = tid >> 5, cc = (tid & 31) << 1;
    const float den = fmaxf(denA[r], 1e-30f);
    const float rden = 1.0f / den;
    Mlds[r][cc]   = Macc[r][cc]   * rden;
    Mlds[r][cc+1] = Macc[r][cc+1] * rden;
    if (tid < 32){
      const float dn = denA[tid];
      uaiL[tid] = (dn <= 0.f) ? (1.0f / 8192.0f) : 0.f;
      if (dn <= 0.f) emptyL = 1;
      const float fb = F[r0 + tid];
      const float zb = fb + gmax;
      const float Bb = fmaxf(zb, 0.2f * zb);
      CiL[tid] = Bb + __logf(fmaxf(dn, 1e-30f));
    }
  }
  __syncthreads();

  // ---- empty-row fixup: M1 = colmean(V) (uniform attention) ----
  if (emptyL){
    if (tid < 64){
      float s = 0.f;
      for (int b = 0; b < 128; ++b) s += Vpart[(size_t)b*64 + tid];
      VmeanL[tid] = s * (1.0f / 8192.0f);
    }
    __syncthreads();
    {
      const int r = tid >> 5, cc = (tid & 31) << 1;
      if (uaiL[r] > 0.f){ Mlds[r][cc] = VmeanL[cc]; Mlds[r][cc+1] = VmeanL[cc+1]; }
    }
    __syncthreads();
  }

  // ---- rm2 + activity gate ----
  if (tid < 32){
    float s2 = 0.f;
    #pragma unroll 8
    for (int o = 0; o < 64; ++o) s2 = fmaf(Mlds[tid][o], Mlds[tid][o], s2);
    rm2L[tid] = s2;
    if (sqrtf(s2) > sqrtf(v2minS) - 3.85f) actL = 1;
  }
  __syncthreads();

  if (actL){
    {
      const int r = tid >> 5, cc = (tid & 31) << 1;
      const float a0 = Mlds[r][cc], a1 = Mlds[r][cc+1];
      M1L[r][cc] = a0;  M1L[r][cc+1] = a1;
      Mb16[r][cc] = f2bf(a0); Mb16[r][cc+1] = f2bf(a1);
    }
    const float e1c0 = __expf(fi0 - CiL[lo]);
    const float e2c0 = __expf(0.2f * fi0 - CiL[lo]);
    const float e1c1 = __expf(fi1 - CiL[16 + lo]);
    const float e2c1 = __expf(0.2f * fi1 - CiL[16 + lo]);
    const float uai0 = uaiL[lo], uai1 = uaiL[16 + lo];
    __syncthreads();

    for (int pass = 0; pass < 3; ++pass){
      {
        float* mz = &Macc[0][0];
        for (int k2 = tid; k2 < 32*65; k2 += 1024) mz[k2] = 0.f;
        if (tid < 32) denA[tid] = 0.f;
        if (tid == 0) chgL = 0;
      }
      __syncthreads();
      const float rm20 = rm2L[lo], rm21 = rm2L[16 + lo];
      s8v bM0[2], bM1[2];
      #pragma unroll
      for (int ks = 0; ks < 2; ++ks){
        bM0[ks] = *(const s8v*)&Mb16[lo]     [ks*32 + hi*8];
        bM1[ks] = *(const s8v*)&Mb16[16 + lo][ks*32 + hi*8];
      }

      f4v cacc0[4] = {zero4, zero4, zero4, zero4};
      f4v cacc1[4] = {zero4, zero4, zero4, zero4};
      float cden0 = 0.f, cden1 = 0.f;

      for (int c = w; c < 128; c += 16){
        // dot for both rowgroups: V-tile read shared
        f4v acc0[4] = {zero4, zero4, zero4, zero4};
        f4v acc1[4] = {zero4, zero4, zero4, zero4};
        const short* vb = VbfSw + (size_t)c*4096 + lane*8;
        #pragma unroll
        for (int nt = 0; nt < 4; ++nt){
          #pragma unroll
          for (int ks = 0; ks < 2; ++ks){
            s8v av = *(const s8v*)(vb + (nt*2 + ks)*512);
            acc0[nt] = __builtin_amdgcn_mfma_f32_16x16x32_bf16(av, bM0[ks], acc0[nt], 0, 0, 0);
            acc1[nt] = __builtin_amdgcn_mfma_f32_16x16x32_bf16(av, bM1[ks], acc1[nt], 0, 0, 0);
          }
        }
        // d2 in place (acc becomes d2); trigger per rowgroup
        float dm0 = 1e30f, dm1 = 1e30f;
        #pragma unroll
        for (int nt = 0; nt < 4; ++nt){
          const int jb = (c << 6) + nt*16 + hi*4;
          const f4v v2q = *(const f4v*)(V2arr + jb);
          #pragma unroll
          for (int q = 0; q < 4; ++q){
            const float d0 = fmaf(-2.0f, acc0[nt][q], rm20 + v2q[q]);
            const float d1 = fmaf(-2.0f, acc1[nt][q], rm21 + v2q[q]);
            acc0[nt][q] = d0; acc1[nt][q] = d1;
            dm0 = fminf(dm0, d0); dm1 = fminf(dm1, d1);
          }
        }
        const bool t0 = __any(dm0 < 14.75f);
        const bool t1 = __any(dm1 < 14.75f);
        if (t0 | t1){
          const unsigned long long mrow0 = t0 ? adjbits[(size_t)c * 8192 + i0] : 0ull;
          const unsigned long long mrow1 = t1 ? adjbits[(size_t)c * 8192 + i1] : 0ull;
          s4v wp0[4], wp1[4];
          #pragma unroll
          for (int nt = 0; nt < 4; ++nt){
            const int jb = (c << 6) + nt*16 + hi*4;
            const f4v u0 = *(const f4v*)(EG + jb);
            const f4v u1 = *(const f4v*)(EG + jb + 2);
            const float ega[4] = {u0[0], u0[2], u1[0], u1[2]};
            const float egb[4] = {u0[1], u0[3], u1[1], u1[3]};
            if (t0){
              const unsigned nib = (unsigned)(mrow0 >> (nt*16 + hi*4)) & 0xFu;
              float wv[4];
              #pragma unroll
              for (int q = 0; q < 4; ++q){
                float A = fmaxf(e1c0 * ega[q], e2c0 * egb[q]);
                A = ((nib >> q) & 1u) ? A : uai0;
                const float dist  = sqrtf(fmaxf(acc0[nt][q], 0.f));
                const float delta = fmaxf(__builtin_amdgcn_rcpf(dist + 0.01f) - 0.26f, 0.f);
                const float ww = delta * A;
                cden0 += ww; wv[q] = ww;
              }
              wp0[nt] = pack4(wv[0], wv[1], wv[2], wv[3]);
            }
            if (t1){
              const unsigned nib = (unsigned)(mrow1 >> (nt*16 + hi*4)) & 0xFu;
              float wv[4];
              #pragma unroll
              for (int q = 0; q < 4; ++q){
                float A = fmaxf(e1c1 * ega[q], e2c1 * egb[q]);
                A = ((nib >> q) & 1u) ? A : uai1;
                const float dist  = sqrtf(fmaxf(acc1[nt][q], 0.f));
                const float delta = fmaxf(__builtin_amdgcn_rcpf(dist + 0.01f) - 0.26f, 0.f);
                const float ww = delta * A;
                cden1 += ww; wv[q] = ww;
              }
              wp1[nt] = pack4(wv[0], wv[1], wv[2], wv[3]);
            }
          }
          const short* vt = VTsw + (size_t)c*4096 + lane*8;
          #pragma unroll
          for (int p = 0; p < 2; ++p){
            #pragma unroll
            for (int ot = 0; ot < 4; ++ot){
              s8v v8 = *(const s8v*)(vt + (p*4 + ot)*512);
              s4v aLo = {v8[0], v8[1], v8[2], v8[3]};
              s4v aHi = {v8[4], v8[5], v8[6], v8[7]};
              if (t0){
                cacc0[ot] = mfma16(aLo, wp0[2*p],   cacc0[ot]);
                cacc0[ot] = mfma16(aHi, wp0[2*p+1], cacc0[ot]);
              }
              if (t1){
                cacc1[ot] = mfma16(aLo, wp1[2*p],   cacc1[ot]);
                cacc1[ot] = mfma16(aHi, wp1[2*p+1], cacc1[ot]);
              }
            }
          }
        }
      }

      if (__any(cden0 > 0.f) || __any(cden1 > 0.f)){
        chgL = 1;
        float cd0 = cden0, cd1 = cden1;
        cd0 += __shfl_xor(cd0, 16); cd0 += __shfl_xor(cd0, 32);
        cd1 += __shfl_xor(cd1, 16); cd1 += __shfl_xor(cd1, 32);
        if (hi == 0) atomicAdd(&denA[lo],      cd0);
        if (hi == 1) atomicAdd(&denA[16 + lo], cd1);
        #pragma unroll
        for (int ot = 0; ot < 4; ++ot)
          #pragma unroll
          for (int q = 0; q < 4; ++q){
            atomicAdd(&Macc[lo]     [ot*16 + hi*4 + q], cacc0[ot][q]);
            atomicAdd(&Macc[16 + lo][ot*16 + hi*4 + q], cacc1[ot][q]);
          }
      }
      __syncthreads();
      if (!chgL) break;   // M unchanged -> later passes are exact no-ops
      {
        const int r = tid >> 5, cc = (tid & 31) << 1;
        const float rden = 1.0f / (0.01f + denA[r]);
        const float n0 = fmaf(0.01f, M1L[r][cc],   Macc[r][cc])   * rden;
        const float n1 = fmaf(0.01f, M1L[r][cc+1], Macc[r][cc+1]) * rden;
        Mlds[r][cc] = n0;  Mlds[r][cc+1] = n1;
        Mb16[r][cc] = f2bf(n0); Mb16[r][cc+1] = f2bf(n1);
      }
      __syncthreads();
      if (tid < 32){
        float s2 = 0.f;
        #pragma unroll 8
        for (int o = 0; o < 64; ++o) s2 = fmaf(Mlds[tid][o], Mlds[tid][o], s2);
        rm2L[tid] = s2;
      }
      __syncthreads();
    }
  }
  __syncthreads();

  // ---- epilogue: elu -> out (32 rows) ----
  #pragma unroll
  for (int rr = 0; rr < 2; ++rr){
    const int ir = w*2 + rr;
    const float v = Mlds[ir][lane];
    out[(size_t)(r0 + ir) * 64 + lane] = (v > 0.f) ? v : (__expf(v) - 1.0f);
  }
}

extern "C" void kernel_launch(void* const* d_in, const int* in_sizes, int n_in,
                              void* d_out, int out_size, void* d_ws, size_t ws_size,
                              hipStream_t stream){
  (void)in_sizes; (void)n_in; (void)out_size; (void)ws_size;
  const int*   adj = (const int*)d_in[0];
  const float* x   = (const float*)d_in[1];
  const float* W   = (const float*)d_in[2];
  const float* a   = (const float*)d_in[3];
  float* out = (float*)d_out;
  char* ws = (char*)d_ws;

  float* h     = (float*)(ws);                                 // 2 MB
  short* VbfSw = (short*)(ws + (2u << 20));                    // 1 MB
  short* VTsw  = (short*)(ws + (3u << 20));                    // 1 MB
  float* F     = (float*)(ws + (4u << 20));                    // 32 KB
  float* V2arr = (float*)(ws + (4u << 20) + (32u << 10));      // 32 KB
  float2* EG   = (float2*)(ws + (4u << 20) + (64u << 10));     // 64 KB
  float* Vpart = (float*)(ws + (4u << 20) + (128u << 10));     // 32 KB
  float* Pv2   = (float*)(ws + (4u << 20) + (160u << 10));     // 512 B
  float* Pg    = (float*)(ws + (4u << 20) + (161u << 10));     // 512 B
  unsigned long long* adjbits = (unsigned long long*)(ws + (5u << 20)); // 8 MB

  k_h    <<<256, 256, 0, stream>>>(x, W, h);
  k_prep <<<128, 256, 0, stream>>>(h, a, VbfSw, VTsw, F, EG, V2arr, Pv2, Pg, Vpart);
  k_fused<<<256, 1024, 0, stream>>>(adj, EG, V2arr, F, Pv2, Pg, Vpart, VbfSw, VTsw, adjbits, out);
}